// Round 8
// baseline (413.551 us; speedup 1.0000x reference)
//
#include <hip/hip_runtime.h>
#include <hip/hip_bf16.h>

#define N_TOK 4096
#define DIM   1024
#define VOCAB 32000
#define BM 128
#define BN 128
#define BKB 64           // K-stage depth in BYTES; dbuf'd 2x in the SAME 32 KB LDS
#define SMOOTH 0.1f

typedef __attribute__((ext_vector_type(4))) float float4v;
typedef __attribute__((ext_vector_type(2))) long long2v;

// f32 -> fp8 e4m3 (OCP, HW cvt) for BOTH tensors in one dispatch.
// W is pre-scaled by 16 (2^4) to escape e4m3's subnormal range
// (|w| <= 0.0136 < 2^-6 min-normal); the GEMM epilogue folds 2^-4 back out.
// Numerics of this path harness-validated in R3-R7 (absmax 0.0).
__global__ void cvt_fp8_2(const float* __restrict__ a, unsigned* __restrict__ da, int n8a,
                          const float* __restrict__ b, unsigned* __restrict__ db, int n8b) {
  int i = blockIdx.x * blockDim.x + threadIdx.x;
  const float4* s; uint2* d; int j; float scl;
  if (i < n8a)            { s = (const float4*)a; d = (uint2*)da; j = i;        scl = 1.f;  }
  else if (i < n8a + n8b) { s = (const float4*)b; d = (uint2*)db; j = i - n8a;  scl = 16.f; }
  else return;
  float4 v0 = s[j * 2], v1 = s[j * 2 + 1];
  unsigned lo = 0, hi = 0;
  lo = __builtin_amdgcn_cvt_pk_fp8_f32(v0.x * scl, v0.y * scl, lo, false);
  lo = __builtin_amdgcn_cvt_pk_fp8_f32(v0.z * scl, v0.w * scl, lo, true);
  hi = __builtin_amdgcn_cvt_pk_fp8_f32(v1.x * scl, v1.y * scl, hi, false);
  hi = __builtin_amdgcn_cvt_pk_fp8_f32(v1.z * scl, v1.w * scl, hi, true);
  uint2 o; o.x = lo; o.y = hi;
  d[j] = o;
}

__device__ __forceinline__ void gload_lds16(const void* g, void* l) {
  __builtin_amdgcn_global_load_lds((const __attribute__((address_space(1))) unsigned int*)g,
                                   (__attribute__((address_space(3))) unsigned int*)l,
                                   16, 0, 0);
}

// logit[n, y_n] in exact f32: one wave per token row (keeps the NLL term at
// full precision independent of the fp8 GEMM path).
__global__ __launch_bounds__(256)
void tgt_dot(const float* __restrict__ x, const float* __restrict__ W,
             const int* __restrict__ y, float* __restrict__ tgtRow) {
  const int n = blockIdx.x * 4 + (threadIdx.x >> 6);
  const int lane = threadIdx.x & 63;
  const float4* xr = (const float4*)(x + (size_t)n * DIM);
  const float4* wr = (const float4*)(W + (size_t)y[n] * DIM);
  float d = 0.f;
#pragma unroll
  for (int i = 0; i < 4; ++i) {
    float4 a = xr[lane + 64 * i], b = wr[lane + 64 * i];
    d += a.x * b.x + a.y * b.y + a.z * b.z + a.w * b.w;
  }
#pragma unroll
  for (int off = 32; off > 0; off >>= 1) d += __shfl_xor(d, off, 64);
  if (lane == 0) tgtRow[n] = d;
}

// C = X8[4096,1024] * W8[32000,1024]^T (fp8 e4m3, mfma 16x16x32) with fused
// per-row sum(exp)/sum.
// R7 state: conflicts 0, no spill, 1365 TF, MfmaUtil 62%. Remaining stall:
// per-stage full vmcnt(0) drain exposes global->LDS latency. This round:
// BKB=64 DOUBLE BUFFER in the same 32 KB (occupancy preserved, unlike
// m99/m100's 64 KB dbuf), issue next-stage loads BEFORE compute, counted
// s_waitcnt vmcnt(4) + raw s_barrier (never drain to 0 in the loop) = T3/T4.
// Swizzle re-derived for 64-B rows (4 x 16B colblocks): stored cb c holds
// global c ^ ((row>>1)&3). Reader: global cb = quad at stored quad^s(row);
// byte%128 classes = 2(row&1) x 4(s) = 8 distinct x 2 lanes = 2-way = free;
// quads at consecutive constants (the measured-zero family of R7).
// k-bijection: k = 16*quad + 8*m + b (m = lo/hi 8B of the b128), same map on
// A and B -> exact same dot products (k-order freedom validated R5-R7).
// Raw-barrier discipline: every wave vmcnt(4)s its own current-tile loads
// before BAR1 -> all tile data in LDS when any wave passes; BAR2 separates
// this iter's ds_reads from next iter's stage into the same buffer.
// W pre-scaled x16; epilogue multiplies acc by 2^-4.
__global__ __launch_bounds__(256, 3)
void gemm_ce(const unsigned char* __restrict__ X8, const unsigned char* __restrict__ W8,
             float* __restrict__ rowExp, float* __restrict__ rowSum) {
  __shared__ __align__(16) unsigned char As[2][BM * BKB];  // 2 x 8 KB
  __shared__ __align__(16) unsigned char Bs[2][BN * BKB];  // 2 x 8 KB -> 32 KB total

  const int ib = blockIdx.x;   // token tile (32)
  const int jb = blockIdx.y;   // vocab tile (250)
  const int row0 = ib * BM;
  const int col0 = jb * BN;

  const int tid  = threadIdx.x;
  const int wv   = tid >> 6;
  const int lane = tid & 63;
  const int wr = wv >> 1, wc = wv & 1;
  const int quad = lane >> 4;
  const int r16  = lane & 15;
  // staging map: 1 KB per inst = 16 rows x 4 colblocks; LDS dest linear at
  // base+lane*16; lane FETCHES global colblock (lane&3) ^ ((row>>1)&3).
  const int lrow4 = lane >> 2;                        // row within 16-row slab
  const int gcb4  = (lane & 3) ^ ((lane >> 3) & 3);   // pre-swizzled source cb
  const int s4    = (r16 >> 1) & 3;                   // reader's swizzle class

  const unsigned char* pAx = X8 + (size_t)(row0 + wv * 16 + lrow4) * DIM + gcb4 * 16;
  const unsigned char* pBx = W8 + (size_t)(col0 + wv * 16 + lrow4) * DIM + gcb4 * 16;

  // per wave: 2 A-slabs (rows wv*16, 64+wv*16) + 2 B-slabs = 4 gload_lds/stage
#define STAGE(b, kt) do { \
    gload_lds16(pAx + (kt) * BKB,            &As[b][(wv * 16) * BKB]); \
    gload_lds16(pAx + 64 * DIM + (kt) * BKB, &As[b][(64 + wv * 16) * BKB]); \
    gload_lds16(pBx + (kt) * BKB,            &Bs[b][(wv * 16) * BKB]); \
    gload_lds16(pBx + 64 * DIM + (kt) * BKB, &Bs[b][(64 + wv * 16) * BKB]); \
  } while (0)

  float4v acc[4][4];
#pragma unroll
  for (int i = 0; i < 4; ++i)
#pragma unroll
    for (int j = 0; j < 4; ++j) acc[i][j] = (float4v){0.f, 0.f, 0.f, 0.f};

  const int cbOff = (quad ^ s4) * 16;   // stored slot of global cb = quad

  STAGE(0, 0);                          // prologue: tile 0 -> buf 0
  int cur = 0;

#pragma unroll 1
  for (int t = 0; t < DIM / BKB; ++t) {   // 16 stages
    if (t < DIM / BKB - 1) {
      STAGE(cur ^ 1, t + 1);              // issue-early: next tile in flight
      asm volatile("s_waitcnt vmcnt(4)" ::: "memory");   // current landed, next pending
    } else {
      asm volatile("s_waitcnt vmcnt(0)" ::: "memory");   // drain last tile
    }
    __builtin_amdgcn_s_barrier();         // BAR1: all waves' current loads in LDS
    __builtin_amdgcn_sched_barrier(0);    // no ds_read hoists above BAR1

    long2v bf[4];
#pragma unroll
    for (int j = 0; j < 4; ++j)
      bf[j] = *(const long2v*)&Bs[cur][(wc * 64 + j * 16 + r16) * BKB + cbOff];
#pragma unroll
    for (int i = 0; i < 4; ++i) {
      const long2v af = *(const long2v*)&As[cur][(wr * 64 + i * 16 + r16) * BKB + cbOff];
#pragma unroll
      for (int j = 0; j < 4; ++j) {
        acc[i][j] = __builtin_amdgcn_mfma_f32_16x16x32_fp8_fp8(af.x, bf[j].x, acc[i][j], 0, 0, 0);
        acc[i][j] = __builtin_amdgcn_mfma_f32_16x16x32_fp8_fp8(af.y, bf[j].y, acc[i][j], 0, 0, 0);
      }
    }

    asm volatile("" ::: "memory");        // ds_reads stay above BAR2
    __builtin_amdgcn_s_barrier();         // BAR2: reads done before next stage clobbers
    asm volatile("" ::: "memory");        // next iter's stage stays below BAR2
    cur ^= 1;
  }

  // Fused epilogue (proven R0 version): per-row sum(exp(logit)), sum(logit).
  // C/D layout: col = r16, row = quad*4 + reg (within each 16x16 tile).
  // acc carries W's x16 prescale -> fold out 2^-4 here.
#pragma unroll
  for (int i = 0; i < 4; ++i)
#pragma unroll
    for (int r = 0; r < 4; ++r) {
      float se = 0.f, ss = 0.f;
#pragma unroll
      for (int j = 0; j < 4; ++j) {
        const float v = acc[i][j][r] * 0.0625f;
        ss += v;
        se += __expf(v);
      }
#pragma unroll
      for (int off = 1; off < 16; off <<= 1) {
        se += __shfl_xor(se, off, 64);
        ss += __shfl_xor(ss, off, 64);
      }
      if (r16 == 0) {
        const int rloc = wr * 64 + i * 16 + quad * 4 + r;
        atomicAdd(&rowExp[row0 + rloc], se);
        atomicAdd(&rowSum[row0 + rloc], ss);
      }
    }
}

// loss = (1/N) sum lse - (1-s)/N * sum tgt - s/(N*V) * sum(all logits)
__global__ void finalize_kernel(const float* __restrict__ rowExp, const float* __restrict__ rowSum,
                                const float* __restrict__ tgtRow, float* __restrict__ out) {
  __shared__ float s1[256], s2[256], s3[256];
  const int t = threadIdx.x;
  float a = 0.f, b = 0.f, c = 0.f;
  for (int n = t; n < N_TOK; n += 256) {
    a += logf(rowExp[n]);
    b += rowSum[n];
    c += tgtRow[n];
  }
  s1[t] = a; s2[t] = b; s3[t] = c;
  __syncthreads();
  for (int o = 128; o > 0; o >>= 1) {
    if (t < o) { s1[t] += s1[t + o]; s2[t] += s2[t + o]; s3[t] += s3[t + o]; }
    __syncthreads();
  }
  if (t == 0) {
    const float inviN = 1.0f / (float)N_TOK;
    out[0] = s1[0] * inviN
           - (1.0f - SMOOTH) * s3[0] * inviN
           - SMOOTH * s2[0] / ((float)N_TOK * (float)VOCAB);
  }
}

extern "C" void kernel_launch(void* const* d_in, const int* in_sizes, int n_in,
                              void* d_out, int out_size, void* d_ws, size_t ws_size,
                              hipStream_t stream) {
  const float* x = (const float*)d_in[0];
  const float* W = (const float*)d_in[1];
  const int*   y = (const int*)d_in[2];
  float* out = (float*)d_out;

  char* ws = (char*)d_ws;
  float* rowExp = (float*)(ws);              // 4096 f32
  float* rowSum = (float*)(ws + 16384);      // 4096 f32
  float* tgtRow = (float*)(ws + 32768);      // 4096 f32 (fully written, no memset)
  unsigned char* X8 = (unsigned char*)(ws + 65536);                          // 4.2 MB
  unsigned char* W8 = (unsigned char*)(ws + 65536 + (size_t)N_TOK * DIM);    // 32.8 MB

  hipMemsetAsync(ws, 0, 32768, stream);  // zero rowExp/rowSum (ws poisoned 0xAA)

  tgt_dot<<<N_TOK / 4, 256, 0, stream>>>(x, W, y, tgtRow);

  const int n8x = N_TOK * DIM / 8, n8w = VOCAB * DIM / 8;
  cvt_fp8_2<<<(n8x + n8w + 255) / 256, 256, 0, stream>>>(x, (unsigned*)X8, n8x, W, (unsigned*)W8, n8w);

  dim3 grid(N_TOK / BM, VOCAB / BN);  // (32, 250): token-fastest for XCD locality
  gemm_ce<<<grid, 256, 0, stream>>>(X8, W8, rowExp, rowSum);

  finalize_kernel<<<1, 256, 0, stream>>>(rowExp, rowSum, tgtRow, out);
}

// Round 9
// 411.685 us; speedup vs baseline: 1.0045x; 1.0045x over previous
//
#include <hip/hip_runtime.h>
#include <hip/hip_bf16.h>

#define N_TOK 4096
#define DIM   1024
#define VOCAB 32000
#define BM 128
#define BN 128
#define BKB 128          // K-stage depth in BYTES = 128 fp8 elems (rows stay 128 B)
#define SMOOTH 0.1f

typedef __attribute__((ext_vector_type(4))) float float4v;
typedef __attribute__((ext_vector_type(2))) long long2v;

// f32 -> fp8 e4m3 (OCP, HW cvt) for BOTH tensors in one dispatch.
// W is pre-scaled by 16 (2^4) to escape e4m3's subnormal range
// (|w| <= 0.0136 < 2^-6 min-normal); the GEMM epilogue folds 2^-4 back out.
// Numerics of this path harness-validated in R3-R8 (absmax 0.0).
__global__ void cvt_fp8_2(const float* __restrict__ a, unsigned* __restrict__ da, int n8a,
                          const float* __restrict__ b, unsigned* __restrict__ db, int n8b) {
  int i = blockIdx.x * blockDim.x + threadIdx.x;
  const float4* s; uint2* d; int j; float scl;
  if (i < n8a)            { s = (const float4*)a; d = (uint2*)da; j = i;        scl = 1.f;  }
  else if (i < n8a + n8b) { s = (const float4*)b; d = (uint2*)db; j = i - n8a;  scl = 16.f; }
  else return;
  float4 v0 = s[j * 2], v1 = s[j * 2 + 1];
  unsigned lo = 0, hi = 0;
  lo = __builtin_amdgcn_cvt_pk_fp8_f32(v0.x * scl, v0.y * scl, lo, false);
  lo = __builtin_amdgcn_cvt_pk_fp8_f32(v0.z * scl, v0.w * scl, lo, true);
  hi = __builtin_amdgcn_cvt_pk_fp8_f32(v1.x * scl, v1.y * scl, hi, false);
  hi = __builtin_amdgcn_cvt_pk_fp8_f32(v1.z * scl, v1.w * scl, hi, true);
  uint2 o; o.x = lo; o.y = hi;
  d[j] = o;
}

__device__ __forceinline__ void gload_lds16(const void* g, void* l) {
  __builtin_amdgcn_global_load_lds((const __attribute__((address_space(1))) unsigned int*)g,
                                   (__attribute__((address_space(3))) unsigned int*)l,
                                   16, 0, 0);
}

// logit[n, y_n] in exact f32: one wave per token row (keeps the NLL term at
// full precision independent of the fp8 GEMM path).
__global__ __launch_bounds__(256)
void tgt_dot(const float* __restrict__ x, const float* __restrict__ W,
             const int* __restrict__ y, float* __restrict__ tgtRow) {
  const int n = blockIdx.x * 4 + (threadIdx.x >> 6);
  const int lane = threadIdx.x & 63;
  const float4* xr = (const float4*)(x + (size_t)n * DIM);
  const float4* wr = (const float4*)(W + (size_t)y[n] * DIM);
  float d = 0.f;
#pragma unroll
  for (int i = 0; i < 4; ++i) {
    float4 a = xr[lane + 64 * i], b = wr[lane + 64 * i];
    d += a.x * b.x + a.y * b.y + a.z * b.z + a.w * b.w;
  }
#pragma unroll
  for (int off = 32; off > 0; off >>= 1) d += __shfl_xor(d, off, 64);
  if (lane == 0) tgtRow[n] = d;
}

// C = X8[4096,1024] * W8[32000,1024]^T (fp8 e4m3, mfma 16x16x32) with fused
// per-row sum(exp)/sum. R7 structure verbatim (196.6 us, 1365 TF, 0 bank
// conflicts, no spill): 8 K-stages of BKB=128, single-buffer 2-barrier loop,
// consecutive-constant quad colblocks ((rr*4+quad)^r8 — the measured-zero
// bank family), k-bijection shared by A and B.
// R8 lesson (counted-vmcnt dbuf at BKB=64, -10%): source-level pipelining in
// this family loses to implicit multi-block overlap; barrier count per K-byte
// is what matters. So this round changes ONLY scheduling-environment knobs:
//  1) __launch_bounds__(256,4): nothing caps residency below 4-5 blocks/CU
//     (64 VGPR, 32 KB LDS), yet occupancy sat at ~3.2 blocks. More resident
//     blocks hide each block's vmcnt(0) drain.
//  2) XCD-aware 1D remap: old grid (32,250) x-fastest replicated every
//     W-tile across all 8 XCD L2s (FETCH 130 MB vs 37 MB working set).
//     New: xcd=id&7 owns a contiguous ~31-jb band (4 MB W = its L2),
//     ib-fastest within the band. Bijective: g = xcd*1000 + id/8.
// W pre-scaled x16; epilogue multiplies acc by 2^-4.
__global__ __launch_bounds__(256, 4)
void gemm_ce(const unsigned char* __restrict__ X8, const unsigned char* __restrict__ W8,
             float* __restrict__ rowExp, float* __restrict__ rowSum) {
  __shared__ __align__(16) unsigned char As[BM * BKB];  // 16 KB, [128][128B]
  __shared__ __align__(16) unsigned char Bs[BN * BKB];  // 16 KB

  // XCD-contiguous remap (8000 = 8 * 1000 blocks; 1000 = 31.25 jb-bands)
  const int id  = blockIdx.x;
  const int g   = (id & 7) * 1000 + (id >> 3);
  const int jb  = g >> 5;          // vocab tile 0..249
  const int ib  = g & 31;          // token tile 0..31
  const int row0 = ib * BM;
  const int col0 = jb * BN;

  const int tid  = threadIdx.x;
  const int wv   = tid >> 6;
  const int lane = tid & 63;
  const int wr = wv >> 1, wc = wv & 1;
  const int quad = lane >> 4;
  const int r16  = lane & 15;
  // staging map: 1 KB per inst = 8 rows x 8 colblocks; LDS slot fixed at
  // base+lane*16, lane FETCHES global colblock (lane&7)^(lrow&7).
  const int lrow = lane >> 3;
  const int gcb  = (lane & 7) ^ (lrow & 7);   // swizzled source colblock
  const int r8   = r16 & 7;                   // reader's row&7

  float4v acc[4][4];
#pragma unroll
  for (int i = 0; i < 4; ++i)
#pragma unroll
    for (int j = 0; j < 4; ++j) acc[i][j] = (float4v){0.f, 0.f, 0.f, 0.f};

  for (int kk = 0; kk < DIM; kk += BKB) {   // 8 stages (DIM bytes = elems)
    __syncthreads();   // prior ds_reads done before overwrite
#pragma unroll
    for (int c = 0; c < 4; ++c) {
      const int rA = wv * 32 + c * 8;   // wave-uniform 8-row slab base
      gload_lds16(X8 + (size_t)(row0 + rA + lrow) * DIM + kk + gcb * 16, &As[rA * BKB]);
      gload_lds16(W8 + (size_t)(col0 + rA + lrow) * DIM + kk + gcb * 16, &Bs[rA * BKB]);
    }
    __syncthreads();   // staging visible (vmcnt drain)

#pragma unroll
    for (int rr = 0; rr < 2; ++rr) {
      const int cbOff = ((rr * 4 + quad) ^ r8) * 16;   // consecutive-constant quads
      long2v bf[4];
#pragma unroll
      for (int j = 0; j < 4; ++j)
        bf[j] = *(const long2v*)&Bs[(wc * 64 + j * 16 + r16) * BKB + cbOff];
#pragma unroll
      for (int i = 0; i < 4; ++i) {
        const long2v af = *(const long2v*)&As[(wr * 64 + i * 16 + r16) * BKB + cbOff];
#pragma unroll
        for (int j = 0; j < 4; ++j) {
          acc[i][j] = __builtin_amdgcn_mfma_f32_16x16x32_fp8_fp8(af.x, bf[j].x, acc[i][j], 0, 0, 0);
          acc[i][j] = __builtin_amdgcn_mfma_f32_16x16x32_fp8_fp8(af.y, bf[j].y, acc[i][j], 0, 0, 0);
        }
      }
    }
  }

  // Fused epilogue (proven R0 version): per-row sum(exp(logit)), sum(logit).
  // C/D layout: col = r16, row = quad*4 + reg (within each 16x16 tile).
  // acc carries W's x16 prescale -> fold out 2^-4 here.
#pragma unroll
  for (int i = 0; i < 4; ++i)
#pragma unroll
    for (int r = 0; r < 4; ++r) {
      float se = 0.f, ss = 0.f;
#pragma unroll
      for (int j = 0; j < 4; ++j) {
        const float v = acc[i][j][r] * 0.0625f;
        ss += v;
        se += __expf(v);
      }
#pragma unroll
      for (int off = 1; off < 16; off <<= 1) {
        se += __shfl_xor(se, off, 64);
        ss += __shfl_xor(ss, off, 64);
      }
      if (r16 == 0) {
        const int rloc = wr * 64 + i * 16 + quad * 4 + r;
        atomicAdd(&rowExp[row0 + rloc], se);
        atomicAdd(&rowSum[row0 + rloc], ss);
      }
    }
}

// loss = (1/N) sum lse - (1-s)/N * sum tgt - s/(N*V) * sum(all logits)
__global__ void finalize_kernel(const float* __restrict__ rowExp, const float* __restrict__ rowSum,
                                const float* __restrict__ tgtRow, float* __restrict__ out) {
  __shared__ float s1[256], s2[256], s3[256];
  const int t = threadIdx.x;
  float a = 0.f, b = 0.f, c = 0.f;
  for (int n = t; n < N_TOK; n += 256) {
    a += logf(rowExp[n]);
    b += rowSum[n];
    c += tgtRow[n];
  }
  s1[t] = a; s2[t] = b; s3[t] = c;
  __syncthreads();
  for (int o = 128; o > 0; o >>= 1) {
    if (t < o) { s1[t] += s1[t + o]; s2[t] += s2[t + o]; s3[t] += s3[t + o]; }
    __syncthreads();
  }
  if (t == 0) {
    const float inviN = 1.0f / (float)N_TOK;
    out[0] = s1[0] * inviN
           - (1.0f - SMOOTH) * s3[0] * inviN
           - SMOOTH * s2[0] / ((float)N_TOK * (float)VOCAB);
  }
}

extern "C" void kernel_launch(void* const* d_in, const int* in_sizes, int n_in,
                              void* d_out, int out_size, void* d_ws, size_t ws_size,
                              hipStream_t stream) {
  const float* x = (const float*)d_in[0];
  const float* W = (const float*)d_in[1];
  const int*   y = (const int*)d_in[2];
  float* out = (float*)d_out;

  char* ws = (char*)d_ws;
  float* rowExp = (float*)(ws);              // 4096 f32
  float* rowSum = (float*)(ws + 16384);      // 4096 f32
  float* tgtRow = (float*)(ws + 32768);      // 4096 f32 (fully written, no memset)
  unsigned char* X8 = (unsigned char*)(ws + 65536);                          // 4.2 MB
  unsigned char* W8 = (unsigned char*)(ws + 65536 + (size_t)N_TOK * DIM);    // 32.8 MB

  hipMemsetAsync(ws, 0, 32768, stream);  // zero rowExp/rowSum (ws poisoned 0xAA)

  tgt_dot<<<N_TOK / 4, 256, 0, stream>>>(x, W, y, tgtRow);

  const int n8x = N_TOK * DIM / 8, n8w = VOCAB * DIM / 8;
  cvt_fp8_2<<<(n8x + n8w + 255) / 256, 256, 0, stream>>>(x, (unsigned*)X8, n8x, W, (unsigned*)W8, n8w);

  gemm_ce<<<(N_TOK / BM) * (VOCAB / BN), 256, 0, stream>>>(X8, W8, rowExp, rowSum);

  finalize_kernel<<<1, 256, 0, stream>>>(rowExp, rowSum, tgtRow, out);
}